// Round 9
// baseline (2859.553 us; speedup 1.0000x reference)
//
#include <hip/hip_runtime.h>

#define NN 2048
#define MM 2048
#define KC 8
#define DD 64
#define PN (NN + 4*KC + 32)
#define PM (MM + 4*KC + 32)
#define CPAD (2*NN*MM + NN*NN + MM*MM + 6*(NN+MM) + 256)
#define PADV 3.0e38f
#define LN2F    0.6931471805599453f
#define INVLN2F 1.4426950408889634f
#define NPART (3*KC)

// zr layout (ints): [8..15]=cnt_x, [16..23]=cnt_y, [24..31]=fill_x, [32..39]=fill_y
struct Params {
  const float* x; const float* centers; const float* ftarg;
  const float* y; const int* predy;
  float* out;
  int* zr;
  int* pred_x;
  int* cntx; int* cnty; int* off_x; int* off_y; int* pox; int* poy;
  int* bxy; int* byx; int* bxx; int* byy;    // per-cluster segment bases in Call
  int* tpre;                                 // 33-entry tile prefix table
  float* la; float* lb; int* valid; float* acc;
  float* part;                               // NPART per-block partials
  float* Xp; float* Yp; float* xn; float* yn;
  float* Fab; float* Faa; float* Gab; float* Gbb;   // ping-pong 2*PN / 2*PM
  float* Call;
};

// ---------------- k_pred: zero potentials (incl pads) + kmeans predict + counts ----------------
__global__ void __launch_bounds__(256) k_pred(Params p){
  const int gtid = blockIdx.x*blockDim.x + threadIdx.x;
  const int nth  = gridDim.x*blockDim.x;

  for(int i=gtid;i<2*PN;i+=nth){ p.Fab[i]=0.f; p.Faa[i]=0.f; }
  for(int j=gtid;j<2*PM;j+=nth){ p.Gab[j]=0.f; p.Gbb[j]=0.f; }

  for(int i=gtid;i<NN;i+=nth){
    const float4* xi = (const float4*)(p.x + i*DD);
    float best = 3.4e38f; int bk = 0;
    for(int k=0;k<KC;k++){
      const float4* ck = (const float4*)(p.centers + k*DD);
      float s = 0.f;
      #pragma unroll
      for(int q=0;q<DD/4;q++){ float4 a=xi[q], b=ck[q];
        float dx=a.x-b.x, dy=a.y-b.y, dz=a.z-b.z, dw=a.w-b.w;
        s += dx*dx+dy*dy+dz*dz+dw*dw; }
      if(s < best){ best = s; bk = k; }
    }
    p.pred_x[i] = bk;
    atomicAdd(&p.zr[8+bk], 1);
  }
  for(int j=gtid;j<MM;j+=nth) atomicAdd(&p.zr[16 + p.predy[j]], 1);
}

// ---------------- k_pack: per-block redundant serial phase + pack ----------------
__global__ void __launch_bounds__(256) k_pack(Params p){
  __shared__ int scx[KC], scy[KC];
  __shared__ int sox[KC+1], soy[KC+1], spx[KC], spy[KC];
  __shared__ int sbxy[KC], sbyx[KC], sbxx[KC], sbyy[KC], sval[KC];
  __shared__ float sla[KC], slb[KC];
  const int tid = threadIdx.x;
  const int gtid = blockIdx.x*blockDim.x + tid;
  const int nth  = gridDim.x*blockDim.x;

  if(tid==0){
    int ox=0, oy=0, px=0, py=0; float lf=0.f;
    for(int k=0;k<KC;k++){
      int nk=p.zr[8+k], mk=p.zr[16+k];
      scx[k]=nk; scy[k]=mk;
      sox[k]=ox; soy[k]=oy; spx[k]=px; spy[k]=py;
      ox+=nk; oy+=mk; px=(px+nk+3)&~3; py=(py+mk+3)&~3;
      sla[k] = -logf(fmaxf((float)nk,1.f));
      slb[k] = -logf(fmaxf((float)mk,1.f));
      sval[k] = (nk>0 && mk>0)?1:0;
      float df = (float)nk/(float)NN - p.ftarg[k];
      lf += df*df;
    }
    sox[KC]=ox; soy[KC]=oy;
    int run=0;
    for(int k=0;k<KC;k++){ int nk=scx[k], mk=scy[k]; sbxy[k]=run; run+=nk*((mk+3)&~3); }
    for(int k=0;k<KC;k++){ int nk=scx[k], mk=scy[k]; sbyx[k]=run; run+=mk*((nk+3)&~3); }
    for(int k=0;k<KC;k++){ int nk=scx[k];            sbxx[k]=run; run+=nk*((nk+3)&~3); }
    for(int k=0;k<KC;k++){ int mk=scy[k];            sbyy[k]=run; run+=mk*((mk+3)&~3); }
    if(blockIdx.x==0){
      for(int k=0;k<KC;k++){
        p.cntx[k]=scx[k]; p.cnty[k]=scy[k];
        p.off_x[k]=sox[k]; p.off_y[k]=soy[k];
        p.pox[k]=spx[k]; p.poy[k]=spy[k];
        p.bxy[k]=sbxy[k]; p.byx[k]=sbyx[k]; p.bxx[k]=sbxx[k]; p.byy[k]=sbyy[k];
        p.la[k]=sla[k]; p.lb[k]=slb[k]; p.valid[k]=sval[k];
      }
      int trun=0;
      for(int e=0;e<32;e++){
        int seg=e>>3, k=e&7;
        int nk=scx[k], mk=scy[k];
        int nrows = (seg==0)?nk:(seg==1)?mk:(seg==2)?nk:mk;
        int rs    = (seg==0)?((mk+3)&~3):(seg==1)?((nk+3)&~3):(seg==2)?((nk+3)&~3):((mk+3)&~3);
        p.tpre[e]=trun;
        trun += ((nrows+63)>>6) * ((rs+63)>>6);
      }
      p.tpre[32]=trun;
      *p.acc = lf/(float)KC;
    }
  }
  __syncthreads();

  for(int i=gtid;i<NN;i+=nth){
    int k=p.pred_x[i];
    int pos = sox[k] + atomicAdd(&p.zr[24+k],1);
    const float4* xi=(const float4*)(p.x+i*DD);
    float4* dst=(float4*)(p.Xp+(size_t)pos*DD);
    float s=0.f;
    #pragma unroll
    for(int q=0;q<DD/4;q++){ float4 v=xi[q]; dst[q]=v;
      s += v.x*v.x+v.y*v.y+v.z*v.z+v.w*v.w; }
    p.xn[pos]=s;
  }
  for(int j=gtid;j<MM;j+=nth){
    int k=p.predy[j];
    int pos = soy[k] + atomicAdd(&p.zr[32+k],1);
    const float4* yj=(const float4*)(p.y+j*DD);
    float4* dst=(float4*)(p.Yp+(size_t)pos*DD);
    float s=0.f;
    #pragma unroll
    for(int q=0;q<DD/4;q++){ float4 v=yj[q]; dst[q]=v;
      s += v.x*v.x+v.y*v.y+v.z*v.z+v.w*v.w; }
    p.yn[pos]=s;
  }
}

// ---------------- k4: LDS-tiled cost build (64x64 tiles, B transposed) ----------------
__global__ void __launch_bounds__(256) k4_cost(Params p){
  __shared__ float As[64*68];
  __shared__ float Bt[64*68];
  const int tid = threadIdx.x;
  const int T = p.tpre[32];

  for(int tile=blockIdx.x; tile<T; tile+=gridDim.x){
    int e=0;
    for(int q=1;q<32;q++) if(tile>=p.tpre[q]) e=q;
    int seg=e>>3, k=e&7;
    int nk=p.cntx[k], mk=p.cnty[k];
    int rsx=(nk+3)&~3, rsy=(mk+3)&~3;
    const float *Apts, *Bpts, *nA, *nB; int nrows, ncol, rs, base;
    if(seg==0){ Apts=p.Xp+(size_t)p.off_x[k]*DD; Bpts=p.Yp+(size_t)p.off_y[k]*DD;
      nA=p.xn+p.off_x[k]; nB=p.yn+p.off_y[k]; nrows=nk; ncol=mk; rs=rsy; base=p.bxy[k]; }
    else if(seg==1){ Apts=p.Yp+(size_t)p.off_y[k]*DD; Bpts=p.Xp+(size_t)p.off_x[k]*DD;
      nA=p.yn+p.off_y[k]; nB=p.xn+p.off_x[k]; nrows=mk; ncol=nk; rs=rsx; base=p.byx[k]; }
    else if(seg==2){ Apts=p.Xp+(size_t)p.off_x[k]*DD; Bpts=Apts;
      nA=p.xn+p.off_x[k]; nB=nA; nrows=nk; ncol=nk; rs=rsx; base=p.bxx[k]; }
    else { Apts=p.Yp+(size_t)p.off_y[k]*DD; Bpts=Apts;
      nA=p.yn+p.off_y[k]; nB=nA; nrows=mk; ncol=mk; rs=rsy; base=p.byy[k]; }
    int ntc=(rs+63)>>6;
    int lt = tile - p.tpre[e];
    int tr = lt/ntc, tc = lt - tr*ntc;

    __syncthreads();
    for(int l=tid;l<1024;l+=256){
      int row=l>>4, c4=l&15;
      int gA=tr*64+row;
      float4 va = (gA<nrows)? ((const float4*)Apts)[gA*16+c4] : make_float4(0.f,0.f,0.f,0.f);
      *(float4*)&As[row*68 + c4*4] = va;
      int gB=tc*64+row;
      float4 vb = (gB<ncol)? ((const float4*)Bpts)[gB*16+c4] : make_float4(0.f,0.f,0.f,0.f);
      Bt[(c4*4+0)*68+row]=vb.x; Bt[(c4*4+1)*68+row]=vb.y;
      Bt[(c4*4+2)*68+row]=vb.z; Bt[(c4*4+3)*68+row]=vb.w;
    }
    __syncthreads();

    int tx=tid&15, ty=tid>>4;
    float4 acc[4] = {make_float4(0,0,0,0),make_float4(0,0,0,0),
                     make_float4(0,0,0,0),make_float4(0,0,0,0)};
    for(int kk=0;kk<64;kk+=4){
      float4 a0=*(float4*)&As[(ty*4+0)*68+kk];
      float4 a1=*(float4*)&As[(ty*4+1)*68+kk];
      float4 a2=*(float4*)&As[(ty*4+2)*68+kk];
      float4 a3=*(float4*)&As[(ty*4+3)*68+kk];
      float4 b0=*(float4*)&Bt[(kk+0)*68+tx*4];
      float4 b1=*(float4*)&Bt[(kk+1)*68+tx*4];
      float4 b2=*(float4*)&Bt[(kk+2)*68+tx*4];
      float4 b3=*(float4*)&Bt[(kk+3)*68+tx*4];
      #define ACCROW(i,AI) \
        acc[i].x = fmaf(AI.x,b0.x, fmaf(AI.y,b1.x, fmaf(AI.z,b2.x, fmaf(AI.w,b3.x, acc[i].x)))); \
        acc[i].y = fmaf(AI.x,b0.y, fmaf(AI.y,b1.y, fmaf(AI.z,b2.y, fmaf(AI.w,b3.y, acc[i].y)))); \
        acc[i].z = fmaf(AI.x,b0.z, fmaf(AI.y,b1.z, fmaf(AI.z,b2.z, fmaf(AI.w,b3.z, acc[i].z)))); \
        acc[i].w = fmaf(AI.x,b0.w, fmaf(AI.y,b1.w, fmaf(AI.z,b2.w, fmaf(AI.w,b3.w, acc[i].w))));
      ACCROW(0,a0) ACCROW(1,a1) ACCROW(2,a2) ACCROW(3,a3)
      #undef ACCROW
    }

    int gc0 = tc*64 + tx*4;
    #pragma unroll
    for(int i=0;i<4;i++){
      int gr = tr*64 + ty*4 + i;
      if(gr >= nrows) continue;
      float xr = nA[gr];
      float v[4]; float d[4]={acc[i].x,acc[i].y,acc[i].z,acc[i].w};
      #pragma unroll
      for(int j=0;j<4;j++){
        int gc = gc0+j;
        v[j] = PADV;
        if(gc < ncol) v[j] = 0.5f*fmaxf(xr + nB[gc] - 2.f*d[j], 0.f);
      }
      if(gc0+3 < rs){
        *(float4*)&p.Call[(size_t)base + (size_t)gr*rs + gc0] = make_float4(v[0],v[1],v[2],v[3]);
      } else {
        for(int j=0;j<4;j++) if(gc0+j < rs) p.Call[(size_t)base + (size_t)gr*rs + gc0+j] = v[j];
      }
    }
  }
}

// ---------------- k_chain: all 21 eps-steps + final, 24 independent blocks ----------------
// bid&7 = cluster, bid>>3 = role (0: Fab<->Gab coupled pair, 1: Faa, 2: Gbb).
// Roles never exchange data across the whole schedule -> only __syncthreads needed.
// Row layout: 16 lanes per row (4 rows per wave) -> 4-step shuffle reductions.
__global__ void __launch_bounds__(1024,4) k_chain(Params p){
  const int bid = blockIdx.x;
  const int k    = bid & 7;
  const int role = bid >> 3;
  const int tid = threadIdx.x;
  const int lane = tid & 63;
  const int wv   = tid >> 6;          // 0..15
  const int sub  = lane >> 4;         // row slot 0..3 within wave
  const int l16  = lane & 15;

  const int nk=p.cntx[k], mk=p.cnty[k];
  const int pox=p.pox[k], poy=p.poy[k];
  const int rsx=(nk+3)&~3, rsy=(mk+3)&~3;
  const float la=p.la[k], lb=p.lb[k];
  const int valid=p.valid[k];
  const int bxy=p.bxy[k], byx=p.byx[k], bxx=p.bxx[k], byy=p.byy[k];

  const int nr = (role==0)? (nk+mk) : (role==1? nk : mk);

  const double EMIN=0.05*0.05, S2=0.8*0.8;
  int neps=0; { double e=16.0; while(e>EMIN){neps++; e*=S2;} neps++; }   // 21
  double e_run=16.0;

  for(int it=0; it<neps; ++it){
    float eps=(it==neps-1)?(float)EMIN:(float)e_run;
    e_run*=S2;
    float s1=(1.0f/eps)*INVLN2F;
    int cur=it&1;
    const float* Fo=p.Fab+cur*PN; float* Fn=p.Fab+(1-cur)*PN;
    const float* Go=p.Gab+cur*PM; float* Gn=p.Gab+(1-cur)*PM;
    const float* Ao=p.Faa+cur*PN; float* An=p.Faa+(1-cur)*PN;
    const float* Bo=p.Gbb+cur*PM; float* Bn=p.Gbb+(1-cur)*PM;

    for(int t0=wv*4; t0<nr; t0+=64){
      int t = t0 + sub;
      const float* Cb=p.Call; const float* Pv=p.Call;
      float hb=0.f, old=0.f; float* dst=0; int rs=0;
      bool act = (t<nr);
      if(act){
        if(role==0){
          if(t<nk){ Cb=p.Call+bxy+(size_t)t*rsy; Pv=Go+poy; hb=lb*INVLN2F; rs=rsy;
                    dst=Fn+pox+t; old=Fo[pox+t]; }
          else{ int r=t-nk; Cb=p.Call+byx+(size_t)r*rsx; Pv=Fo+pox; hb=la*INVLN2F; rs=rsx;
                dst=Gn+poy+r; old=Go[poy+r]; }
        } else if(role==1){
          Cb=p.Call+bxx+(size_t)t*rsx; Pv=Ao+pox; hb=la*INVLN2F; rs=rsx;
          dst=An+pox+t; old=Ao[pox+t];
        } else {
          Cb=p.Call+byy+(size_t)t*rsy; Pv=Bo+poy; hb=lb*INVLN2F; rs=rsy;
          dst=Bn+poy+t; old=Bo[poy+t];
        }
      }
      float m=-3.4e38f, s=0.f;
      for(int c0=l16*4; c0<rs; c0+=64){
        float4 cv=*(const float4*)(Cb+c0);
        float4 pv=*(const float4*)(Pv+c0);
        float w0=fmaf(pv.x-cv.x,s1,hb), w1=fmaf(pv.y-cv.y,s1,hb);
        float w2=fmaf(pv.z-cv.z,s1,hb), w3=fmaf(pv.w-cv.w,s1,hb);
        float lm=fmaxf(fmaxf(w0,w1),fmaxf(w2,w3));
        float mn=fmaxf(m,lm);
        s = s*exp2f(m-mn)+(exp2f(w0-mn)+exp2f(w1-mn))+(exp2f(w2-mn)+exp2f(w3-mn));
        m=mn;
      }
      float M=m;
      #pragma unroll
      for(int mm=1;mm<16;mm<<=1) M = fmaxf(M, __shfl_xor(M,mm,64));
      float sc = s*exp2f(m-M);
      #pragma unroll
      for(int mm=1;mm<16;mm<<=1) sc += __shfl_xor(sc,mm,64);
      if(act && l16==0){
        float L = -eps*LN2F*(M+log2f(sc));
        *dst = 0.5f*(old+L);
      }
    }
    __syncthreads();
  }

  // final extrapolation at eps_min + per-block partial (no atomics)
  {
    int cur=neps&1;
    float eps=(float)EMIN, s1=(1.0f/eps)*INVLN2F;
    const float* Fo=p.Fab+cur*PN;
    const float* Go=p.Gab+cur*PM;
    const float* Ao=p.Faa+cur*PN;
    const float* Bo=p.Gbb+cur*PM;
    float part=0.f;
    if(valid){
      for(int t0=wv*4; t0<nr; t0+=64){
        int t = t0 + sub;
        const float* Cb=p.Call; const float* Pv=p.Call;
        float hb=0.f, fv=0.f; int rs=0;
        bool act = (t<nr);
        if(act){
          if(role==0){
            if(t<nk){ Cb=p.Call+bxy+(size_t)t*rsy; Pv=Go+poy; hb=lb*INVLN2F; rs=rsy;
                      fv= 1.f/(float)nk; }
            else{ int r=t-nk; Cb=p.Call+byx+(size_t)r*rsx; Pv=Fo+pox; hb=la*INVLN2F; rs=rsx;
                  fv= 1.f/(float)mk; }
          } else if(role==1){
            Cb=p.Call+bxx+(size_t)t*rsx; Pv=Ao+pox; hb=la*INVLN2F; rs=rsx;
            fv=-1.f/(float)nk;
          } else {
            Cb=p.Call+byy+(size_t)t*rsy; Pv=Bo+poy; hb=lb*INVLN2F; rs=rsy;
            fv=-1.f/(float)mk;
          }
        }
        float m=-3.4e38f, s=0.f;
        for(int c0=l16*4; c0<rs; c0+=64){
          float4 cv=*(const float4*)(Cb+c0);
          float4 pv=*(const float4*)(Pv+c0);
          float w0=fmaf(pv.x-cv.x,s1,hb), w1=fmaf(pv.y-cv.y,s1,hb);
          float w2=fmaf(pv.z-cv.z,s1,hb), w3=fmaf(pv.w-cv.w,s1,hb);
          float lm=fmaxf(fmaxf(w0,w1),fmaxf(w2,w3));
          float mn=fmaxf(m,lm);
          s = s*exp2f(m-mn)+(exp2f(w0-mn)+exp2f(w1-mn))+(exp2f(w2-mn)+exp2f(w3-mn));
          m=mn;
        }
        float M=m;
        #pragma unroll
        for(int mm=1;mm<16;mm<<=1) M = fmaxf(M, __shfl_xor(M,mm,64));
        float sc = s*exp2f(m-M);
        #pragma unroll
        for(int mm=1;mm<16;mm<<=1) sc += __shfl_xor(sc,mm,64);
        if(act && l16==0)
          part += fv * (-eps*LN2F*(M+log2f(sc)));
      }
    }
    // block reduction of part (nonzero only on l16==0 lanes)
    __shared__ float red[16];
    part += __shfl_xor(part,16,64);
    part += __shfl_xor(part,32,64);
    if(lane==0) red[wv]=part;
    __syncthreads();
    if(tid==0){
      float t=0.f;
      #pragma unroll
      for(int i=0;i<16;i++) t+=red[i];
      p.part[bid]=t;
    }
  }
}

// ---------------- k_out: sum 24 partials + filling loss ----------------
__global__ void k_out(Params p){
  if(threadIdx.x==0 && blockIdx.x==0){
    float s = *p.acc;
    for(int i=0;i<NPART;i++) s += p.part[i];
    p.out[0] = s;
  }
}

extern "C" void kernel_launch(void* const* d_in, const int* in_sizes, int n_in,
                              void* d_out, int out_size, void* d_ws, size_t ws_size,
                              hipStream_t stream)
{
  Params p;
  p.x       = (const float*)d_in[0];
  p.centers = (const float*)d_in[1];
  p.ftarg   = (const float*)d_in[2];
  p.y       = (const float*)d_in[3];
  p.predy   = (const int*)d_in[4];
  p.out     = (float*)d_out;

  char* w = (char*)d_ws; size_t o = 0;
  auto A = [&](size_t bytes)->char*{ char* r = w + o; o = (o + bytes + 255) & ~(size_t)255; return r; };
  p.zr   =(int*)A(64*4);
  p.pred_x=(int*)A(NN*4);
  p.cntx =(int*)A(KC*4); p.cnty=(int*)A(KC*4);
  p.off_x=(int*)A(KC*4); p.off_y=(int*)A(KC*4);
  p.pox  =(int*)A(KC*4); p.poy =(int*)A(KC*4);
  p.bxy  =(int*)A(KC*4); p.byx =(int*)A(KC*4);
  p.bxx  =(int*)A(KC*4); p.byy =(int*)A(KC*4);
  p.tpre =(int*)A(33*4);
  p.la=(float*)A(KC*4); p.lb=(float*)A(KC*4); p.valid=(int*)A(KC*4);
  p.acc=(float*)A(4);
  p.part=(float*)A(NPART*4);
  p.Xp=(float*)A((size_t)NN*DD*4); p.Yp=(float*)A((size_t)MM*DD*4);
  p.xn=(float*)A(NN*4); p.yn=(float*)A(MM*4);
  p.Fab=(float*)A((size_t)2*PN*4); p.Faa=(float*)A((size_t)2*PN*4);
  p.Gab=(float*)A((size_t)2*PM*4); p.Gbb=(float*)A((size_t)2*PM*4);
  p.Call=(float*)A((size_t)CPAD*4);

  hipMemsetAsync(p.zr, 0, 64*4, stream);
  hipLaunchKernelGGL(k_pred,  dim3(16),    dim3(256),  0, stream, p);
  hipLaunchKernelGGL(k_pack,  dim3(32),    dim3(256),  0, stream, p);
  hipLaunchKernelGGL(k4_cost, dim3(1024),  dim3(256),  0, stream, p);
  hipLaunchKernelGGL(k_chain, dim3(NPART), dim3(1024), 0, stream, p);
  hipLaunchKernelGGL(k_out,   dim3(1),     dim3(64),   0, stream, p);
}

// Round 10
// 274.875 us; speedup vs baseline: 10.4031x; 10.4031x over previous
//
#include <hip/hip_runtime.h>

#define NN 2048
#define MM 2048
#define KC 8
#define DD 64
#define PN (NN + 4*KC + 32)
#define PM (MM + 4*KC + 32)
#define TOTROWS (2*(NN+MM))
#define CPAD (2*NN*MM + NN*NN + MM*MM + 6*(NN+MM) + 256)
#define PADV 3.0e38f
#define LN2F    0.6931471805599453f
#define INVLN2F 1.4426950408889634f
#define NBLK (TOTROWS/8)      // 1024 blocks, 4 waves/block, 2 rows/wave

// zr layout (ints): [8..15]=cnt_x, [16..23]=cnt_y, [24..31]=fill_x, [32..39]=fill_y
struct Params {
  const float* x; const float* centers; const float* ftarg;
  const float* y; const int* predy;
  float* out;
  int* zr;
  int* pred_x;
  int* cntx; int* cnty; int* off_x; int* off_y; int* pox; int* poy;
  int* bxy; int* byx; int* bxx; int* byy;    // per-cluster segment bases in Call
  int* tpre;                                 // 33-entry tile prefix table
  float* la; float* lb; int* valid; float* acc;
  float* part;                               // NBLK per-block partials (no atomics)
  float* Xp; float* Yp; float* xn; float* yn;
  float* Fab; float* Faa; float* Gab; float* Gbb;   // ping-pong 2*PN / 2*PM
  int4* meta;   // per-row {coff, hoff, rs, bitcast(hb2)}
  float* fin;   // per-row final scale (0 if invalid)
  int* dsti;    // per-row destination index in padded potential array
  float* Call;
};

__device__ __forceinline__ float wredmax(float v){
  #pragma unroll
  for(int m=32;m>=1;m>>=1) v = fmaxf(v, __shfl_xor(v,m,64));
  return v;
}
__device__ __forceinline__ float wredsum(float v){
  #pragma unroll
  for(int m=32;m>=1;m>>=1) v += __shfl_xor(v,m,64);
  return v;
}

// ---------------- k_pred: zero potentials + kmeans predict + counts ----------------
__global__ void __launch_bounds__(256) k_pred(Params p){
  const int gtid = blockIdx.x*blockDim.x + threadIdx.x;
  const int nth  = gridDim.x*blockDim.x;

  for(int i=gtid;i<2*PN;i+=nth){ p.Fab[i]=0.f; p.Faa[i]=0.f; }
  for(int j=gtid;j<2*PM;j+=nth){ p.Gab[j]=0.f; p.Gbb[j]=0.f; }

  for(int i=gtid;i<NN;i+=nth){
    const float4* xi = (const float4*)(p.x + i*DD);
    float best = 3.4e38f; int bk = 0;
    for(int k=0;k<KC;k++){
      const float4* ck = (const float4*)(p.centers + k*DD);
      float s = 0.f;
      #pragma unroll
      for(int q=0;q<DD/4;q++){ float4 a=xi[q], b=ck[q];
        float dx=a.x-b.x, dy=a.y-b.y, dz=a.z-b.z, dw=a.w-b.w;
        s += dx*dx+dy*dy+dz*dz+dw*dw; }
      if(s < best){ best = s; bk = k; }
    }
    p.pred_x[i] = bk;
    atomicAdd(&p.zr[8+bk], 1);
  }
  for(int j=gtid;j<MM;j+=nth) atomicAdd(&p.zr[16 + p.predy[j]], 1);
}

// ---------------- k_pack: per-block redundant serial phase + pack + row meta ----------------
__global__ void __launch_bounds__(256) k_pack(Params p){
  __shared__ int scx[KC], scy[KC];
  __shared__ int sox[KC+1], soy[KC+1], spx[KC], spy[KC];
  __shared__ int sbxy[KC], sbyx[KC], sbxx[KC], sbyy[KC], sval[KC];
  __shared__ float sla[KC], slb[KC];
  const int tid = threadIdx.x;
  const int gtid = blockIdx.x*blockDim.x + tid;
  const int nth  = gridDim.x*blockDim.x;

  if(tid==0){
    int ox=0, oy=0, px=0, py=0; float lf=0.f;
    for(int k=0;k<KC;k++){
      int nk=p.zr[8+k], mk=p.zr[16+k];
      scx[k]=nk; scy[k]=mk;
      sox[k]=ox; soy[k]=oy; spx[k]=px; spy[k]=py;
      ox+=nk; oy+=mk; px=(px+nk+3)&~3; py=(py+mk+3)&~3;
      sla[k] = -logf(fmaxf((float)nk,1.f));
      slb[k] = -logf(fmaxf((float)mk,1.f));
      sval[k] = (nk>0 && mk>0)?1:0;
      float df = (float)nk/(float)NN - p.ftarg[k];
      lf += df*df;
    }
    sox[KC]=ox; soy[KC]=oy;
    int run=0;
    for(int k=0;k<KC;k++){ int nk=scx[k], mk=scy[k]; sbxy[k]=run; run+=nk*((mk+3)&~3); }
    for(int k=0;k<KC;k++){ int nk=scx[k], mk=scy[k]; sbyx[k]=run; run+=mk*((nk+3)&~3); }
    for(int k=0;k<KC;k++){ int nk=scx[k];            sbxx[k]=run; run+=nk*((nk+3)&~3); }
    for(int k=0;k<KC;k++){ int mk=scy[k];            sbyy[k]=run; run+=mk*((mk+3)&~3); }
    if(blockIdx.x==0){
      for(int k=0;k<KC;k++){
        p.cntx[k]=scx[k]; p.cnty[k]=scy[k];
        p.off_x[k]=sox[k]; p.off_y[k]=soy[k];
        p.pox[k]=spx[k]; p.poy[k]=spy[k];
        p.bxy[k]=sbxy[k]; p.byx[k]=sbyx[k]; p.bxx[k]=sbxx[k]; p.byy[k]=sbyy[k];
        p.la[k]=sla[k]; p.lb[k]=slb[k]; p.valid[k]=sval[k];
      }
      int trun=0;
      for(int e=0;e<32;e++){
        int seg=e>>3, k=e&7;
        int nk=scx[k], mk=scy[k];
        int nrows = (seg==0)?nk:(seg==1)?mk:(seg==2)?nk:mk;
        int rs    = (seg==0)?((mk+3)&~3):(seg==1)?((nk+3)&~3):(seg==2)?((nk+3)&~3):((mk+3)&~3);
        p.tpre[e]=trun;
        trun += ((nrows+63)>>6) * ((rs+63)>>6);
      }
      p.tpre[32]=trun;
      *p.acc = lf/(float)KC;
    }
  }
  __syncthreads();

  // pack (positions via global fill counters)
  for(int i=gtid;i<NN;i+=nth){
    int k=p.pred_x[i];
    int pos = sox[k] + atomicAdd(&p.zr[24+k],1);
    const float4* xi=(const float4*)(p.x+i*DD);
    float4* dst=(float4*)(p.Xp+(size_t)pos*DD);
    float s=0.f;
    #pragma unroll
    for(int q=0;q<DD/4;q++){ float4 v=xi[q]; dst[q]=v;
      s += v.x*v.x+v.y*v.y+v.z*v.z+v.w*v.w; }
    p.xn[pos]=s;
  }
  for(int j=gtid;j<MM;j+=nth){
    int k=p.predy[j];
    int pos = soy[k] + atomicAdd(&p.zr[32+k],1);
    const float4* yj=(const float4*)(p.y+j*DD);
    float4* dst=(float4*)(p.Yp+(size_t)pos*DD);
    float s=0.f;
    #pragma unroll
    for(int q=0;q<DD/4;q++){ float4 v=yj[q]; dst[q]=v;
      s += v.x*v.x+v.y*v.y+v.z*v.z+v.w*v.w; }
    p.yn[pos]=s;
  }

  // per-row metadata
  for(int row=gtid; row<TOTROWS; row+=nth){
    int grp = (row>=NN) + (row>=NN+MM) + (row>=2*NN+MM);
    int pidx = row - ((grp==0)?0:(grp==1)?NN:(grp==2)?(NN+MM):(2*NN+MM));
    const int* offs = (grp==0||grp==2)? sox : soy;
    int k=0;
    #pragma unroll
    for(int q=1;q<KC;q++) if(pidx>=offs[q]) k=q;
    int r = pidx - offs[k];
    int nk=scx[k], mk=scy[k];
    int rsx=(nk+3)&~3, rsy=(mk+3)&~3;
    int coff, rs, di; float hc, fv; int hoff;
    if(grp==0){ rs=rsy; coff=sbxy[k]+r*rs; hoff=spy[k]; hc=slb[k]; di=spx[k]+r;
      fv = sval[k] ?  1.f/(float)nk : 0.f; }
    else if(grp==1){ rs=rsx; coff=sbyx[k]+r*rs; hoff=spx[k]; hc=sla[k]; di=spy[k]+r;
      fv = sval[k] ?  1.f/(float)mk : 0.f; }
    else if(grp==2){ rs=rsx; coff=sbxx[k]+r*rs; hoff=spx[k]; hc=sla[k]; di=spx[k]+r;
      fv = sval[k] ? -1.f/(float)nk : 0.f; }
    else { rs=rsy; coff=sbyy[k]+r*rs; hoff=spy[k]; hc=slb[k]; di=spy[k]+r;
      fv = sval[k] ? -1.f/(float)mk : 0.f; }
    p.meta[row] = make_int4(coff, hoff, rs, __float_as_int(hc*INVLN2F));
    p.fin[row]  = fv;
    p.dsti[row] = di;
  }
}

// ---------------- k4: LDS-tiled cost build (64x64 tiles, B transposed) ----------------
__global__ void __launch_bounds__(256) k4_cost(Params p){
  __shared__ float As[64*68];
  __shared__ float Bt[64*68];
  const int tid = threadIdx.x;
  const int T = p.tpre[32];

  for(int tile=blockIdx.x; tile<T; tile+=gridDim.x){
    int e=0;
    for(int q=1;q<32;q++) if(tile>=p.tpre[q]) e=q;
    int seg=e>>3, k=e&7;
    int nk=p.cntx[k], mk=p.cnty[k];
    int rsx=(nk+3)&~3, rsy=(mk+3)&~3;
    const float *Apts, *Bpts, *nA, *nB; int nrows, ncol, rs, base;
    if(seg==0){ Apts=p.Xp+(size_t)p.off_x[k]*DD; Bpts=p.Yp+(size_t)p.off_y[k]*DD;
      nA=p.xn+p.off_x[k]; nB=p.yn+p.off_y[k]; nrows=nk; ncol=mk; rs=rsy; base=p.bxy[k]; }
    else if(seg==1){ Apts=p.Yp+(size_t)p.off_y[k]*DD; Bpts=p.Xp+(size_t)p.off_x[k]*DD;
      nA=p.yn+p.off_y[k]; nB=p.xn+p.off_x[k]; nrows=mk; ncol=nk; rs=rsx; base=p.byx[k]; }
    else if(seg==2){ Apts=p.Xp+(size_t)p.off_x[k]*DD; Bpts=Apts;
      nA=p.xn+p.off_x[k]; nB=nA; nrows=nk; ncol=nk; rs=rsx; base=p.bxx[k]; }
    else { Apts=p.Yp+(size_t)p.off_y[k]*DD; Bpts=Apts;
      nA=p.yn+p.off_y[k]; nB=nA; nrows=mk; ncol=mk; rs=rsy; base=p.byy[k]; }
    int ntc=(rs+63)>>6;
    int lt = tile - p.tpre[e];
    int tr = lt/ntc, tc = lt - tr*ntc;

    __syncthreads();
    for(int l=tid;l<1024;l+=256){
      int row=l>>4, c4=l&15;
      int gA=tr*64+row;
      float4 va = (gA<nrows)? ((const float4*)Apts)[gA*16+c4] : make_float4(0.f,0.f,0.f,0.f);
      *(float4*)&As[row*68 + c4*4] = va;
      int gB=tc*64+row;
      float4 vb = (gB<ncol)? ((const float4*)Bpts)[gB*16+c4] : make_float4(0.f,0.f,0.f,0.f);
      Bt[(c4*4+0)*68+row]=vb.x; Bt[(c4*4+1)*68+row]=vb.y;
      Bt[(c4*4+2)*68+row]=vb.z; Bt[(c4*4+3)*68+row]=vb.w;
    }
    __syncthreads();

    int tx=tid&15, ty=tid>>4;
    float4 acc[4] = {make_float4(0,0,0,0),make_float4(0,0,0,0),
                     make_float4(0,0,0,0),make_float4(0,0,0,0)};
    for(int kk=0;kk<64;kk+=4){
      float4 a0=*(float4*)&As[(ty*4+0)*68+kk];
      float4 a1=*(float4*)&As[(ty*4+1)*68+kk];
      float4 a2=*(float4*)&As[(ty*4+2)*68+kk];
      float4 a3=*(float4*)&As[(ty*4+3)*68+kk];
      float4 b0=*(float4*)&Bt[(kk+0)*68+tx*4];
      float4 b1=*(float4*)&Bt[(kk+1)*68+tx*4];
      float4 b2=*(float4*)&Bt[(kk+2)*68+tx*4];
      float4 b3=*(float4*)&Bt[(kk+3)*68+tx*4];
      #define ACCROW(i,AI) \
        acc[i].x = fmaf(AI.x,b0.x, fmaf(AI.y,b1.x, fmaf(AI.z,b2.x, fmaf(AI.w,b3.x, acc[i].x)))); \
        acc[i].y = fmaf(AI.x,b0.y, fmaf(AI.y,b1.y, fmaf(AI.z,b2.y, fmaf(AI.w,b3.y, acc[i].y)))); \
        acc[i].z = fmaf(AI.x,b0.z, fmaf(AI.y,b1.z, fmaf(AI.z,b2.z, fmaf(AI.w,b3.z, acc[i].z)))); \
        acc[i].w = fmaf(AI.x,b0.w, fmaf(AI.y,b1.w, fmaf(AI.z,b2.w, fmaf(AI.w,b3.w, acc[i].w))));
      ACCROW(0,a0) ACCROW(1,a1) ACCROW(2,a2) ACCROW(3,a3)
      #undef ACCROW
    }

    int gc0 = tc*64 + tx*4;
    #pragma unroll
    for(int i=0;i<4;i++){
      int gr = tr*64 + ty*4 + i;
      if(gr >= nrows) continue;
      float xr = nA[gr];
      float v[4]; float d[4]={acc[i].x,acc[i].y,acc[i].z,acc[i].w};
      #pragma unroll
      for(int j=0;j<4;j++){
        int gc = gc0+j;
        v[j] = PADV;
        if(gc < ncol) v[j] = 0.5f*fmaxf(xr + nB[gc] - 2.f*d[j], 0.f);
      }
      if(gc0+3 < rs){
        *(float4*)&p.Call[(size_t)base + (size_t)gr*rs + gc0] = make_float4(v[0],v[1],v[2],v[3]);
      } else {
        for(int j=0;j<4;j++) if(gc0+j < rs) p.Call[(size_t)base + (size_t)gr*rs + gc0+j] = v[j];
      }
    }
  }
}

// online-LSE stream step: one 128B chunk of one row
#define LSE_STEP(Ci,Pi,hi,mi,si) { \
  float4 cv=*(const float4*)(Ci+c0), pv=*(const float4*)(Pi+c0); \
  float w0=fmaf(pv.x-cv.x,s1,hi), w1=fmaf(pv.y-cv.y,s1,hi); \
  float w2=fmaf(pv.z-cv.z,s1,hi), w3=fmaf(pv.w-cv.w,s1,hi); \
  float lm=fmaxf(fmaxf(w0,w1),fmaxf(w2,w3)); \
  float mn=fmaxf(mi,lm); \
  si = si*exp2f(mi-mn) + (exp2f(w0-mn)+exp2f(w1-mn)) + (exp2f(w2-mn)+exp2f(w3-mn)); \
  mi = mn; }

// ---------------- k_iter: one Jacobi eps-step, 2 rows per wave (round-7 proven shape) ----------------
__global__ void __launch_bounds__(256) k_iter(Params p, float eps, int cur){
  const int w = blockIdx.x*4 + (threadIdx.x>>6);
  const int lane = threadIdx.x & 63;
  const int r0 = w*2, r1 = r0+1;
  const int grp = (r0>=NN) + (r0>=NN+MM) + (r0>=2*NN+MM);   // pairs never straddle
  const float* po; float* fam; int famN;
  if(grp==0){ po=p.Gab+cur*PM; fam=p.Fab; famN=PN; }
  else if(grp==1){ po=p.Fab+cur*PN; fam=p.Gab; famN=PM; }
  else if(grp==2){ po=p.Faa+cur*PN; fam=p.Faa; famN=PN; }
  else { po=p.Gbb+cur*PM; fam=p.Gbb; famN=PM; }

  int4 m0 = p.meta[r0], m1 = p.meta[r1];
  const float* C0=p.Call+m0.x; const float* P0=po+m0.y; float h0=__int_as_float(m0.w);
  const float* C1=p.Call+m1.x; const float* P1=po+m1.y; float h1=__int_as_float(m1.w);
  const int rs0=m0.z, rs1=m1.z, rsm = rs0>rs1?rs0:rs1;
  const float s1 = (1.0f/eps)*INVLN2F;

  float mA=-3.4e38f,sA=0.f,mB=-3.4e38f,sB=0.f;
  for(int c0=lane*4; c0<rsm; c0+=256){
    if(c0<rs0) LSE_STEP(C0,P0,h0,mA,sA)
    if(c0<rs1) LSE_STEP(C1,P1,h1,mB,sB)
  }
  float MA=wredmax(mA); float SA=wredsum(sA*exp2f(mA-MA));
  float MB=wredmax(mB); float SB=wredsum(sB*exp2f(mB-MB));
  float LA = -eps*LN2F*(MA + log2f(SA));
  float LB = -eps*LN2F*(MB + log2f(SB));

  if(lane==0){
    int d0=p.dsti[r0], d1=p.dsti[r1];
    float* fn = fam + (1-cur)*famN;
    const float* fo = fam + cur*famN;
    fn[d0] = 0.5f*(fo[d0]+LA);
    fn[d1] = 0.5f*(fo[d1]+LB);
  }
}

// ---------------- k_final: extrapolation at eps_min, per-block partial (NO atomics) ----------------
__global__ void __launch_bounds__(256) k_final(Params p, float eps, int cur){
  __shared__ float sp[4];
  const int w = blockIdx.x*4 + (threadIdx.x>>6);
  const int lane = threadIdx.x & 63;
  const int wv = threadIdx.x>>6;
  const int r0 = w*2, r1 = r0+1;
  const int grp = (r0>=NN) + (r0>=NN+MM) + (r0>=2*NN+MM);
  const float* po = (grp==0)?(p.Gab+cur*PM):(grp==1)?(p.Fab+cur*PN)
                   :(grp==2)?(p.Faa+cur*PN):(p.Gbb+cur*PM);

  int4 m0 = p.meta[r0], m1 = p.meta[r1];
  float fv0=p.fin[r0], fv1=p.fin[r1];
  const float* C0=p.Call+m0.x; const float* P0=po+m0.y; float h0=__int_as_float(m0.w);
  const float* C1=p.Call+m1.x; const float* P1=po+m1.y; float h1=__int_as_float(m1.w);
  const int rs0=m0.z, rs1=m1.z, rsm = rs0>rs1?rs0:rs1;
  const float s1 = (1.0f/eps)*INVLN2F;

  float mA=-3.4e38f,sA=0.f,mB=-3.4e38f,sB=0.f;
  for(int c0=lane*4; c0<rsm; c0+=256){
    if(c0<rs0) LSE_STEP(C0,P0,h0,mA,sA)
    if(c0<rs1) LSE_STEP(C1,P1,h1,mB,sB)
  }
  float MA=wredmax(mA); float SA=wredsum(sA*exp2f(mA-MA));
  float MB=wredmax(mB); float SB=wredsum(sB*exp2f(mB-MB));

  if(lane==0){
    float part = 0.f;
    if(fv0!=0.f) part += fv0 * (-eps*LN2F*(MA + log2f(SA)));
    if(fv1!=0.f) part += fv1 * (-eps*LN2F*(MB + log2f(SB)));
    sp[wv] = part;
  }
  __syncthreads();
  if(threadIdx.x==0)
    p.part[blockIdx.x] = sp[0]+sp[1]+sp[2]+sp[3];
}

// ---------------- k_out: sum partials + filling loss, write scalar ----------------
__global__ void __launch_bounds__(256) k_out(Params p){
  __shared__ float red[4];
  float s=0.f;
  for(int i=threadIdx.x;i<NBLK;i+=256) s += p.part[i];
  s = wredsum(s);
  if((threadIdx.x&63)==0) red[threadIdx.x>>6]=s;
  __syncthreads();
  if(threadIdx.x==0)
    p.out[0] = red[0]+red[1]+red[2]+red[3] + *p.acc;
}

extern "C" void kernel_launch(void* const* d_in, const int* in_sizes, int n_in,
                              void* d_out, int out_size, void* d_ws, size_t ws_size,
                              hipStream_t stream)
{
  Params p;
  p.x       = (const float*)d_in[0];
  p.centers = (const float*)d_in[1];
  p.ftarg   = (const float*)d_in[2];
  p.y       = (const float*)d_in[3];
  p.predy   = (const int*)d_in[4];
  p.out     = (float*)d_out;

  char* w = (char*)d_ws; size_t o = 0;
  auto A = [&](size_t bytes)->char*{ char* r = w + o; o = (o + bytes + 255) & ~(size_t)255; return r; };
  p.zr   =(int*)A(64*4);
  p.pred_x=(int*)A(NN*4);
  p.cntx =(int*)A(KC*4); p.cnty=(int*)A(KC*4);
  p.off_x=(int*)A(KC*4); p.off_y=(int*)A(KC*4);
  p.pox  =(int*)A(KC*4); p.poy =(int*)A(KC*4);
  p.bxy  =(int*)A(KC*4); p.byx =(int*)A(KC*4);
  p.bxx  =(int*)A(KC*4); p.byy =(int*)A(KC*4);
  p.tpre =(int*)A(33*4);
  p.la=(float*)A(KC*4); p.lb=(float*)A(KC*4); p.valid=(int*)A(KC*4);
  p.acc=(float*)A(4);
  p.part=(float*)A(NBLK*4);
  p.Xp=(float*)A((size_t)NN*DD*4); p.Yp=(float*)A((size_t)MM*DD*4);
  p.xn=(float*)A(NN*4); p.yn=(float*)A(MM*4);
  p.Fab=(float*)A((size_t)2*PN*4); p.Faa=(float*)A((size_t)2*PN*4);
  p.Gab=(float*)A((size_t)2*PM*4); p.Gbb=(float*)A((size_t)2*PM*4);
  p.meta=(int4*)A((size_t)TOTROWS*16);
  p.fin =(float*)A((size_t)TOTROWS*4);
  p.dsti=(int*)A((size_t)TOTROWS*4);
  p.Call=(float*)A((size_t)CPAD*4);

  hipMemsetAsync(p.zr, 0, 64*4, stream);
  hipLaunchKernelGGL(k_pred,  dim3(16),   dim3(256), 0, stream, p);
  hipLaunchKernelGGL(k_pack,  dim3(32),   dim3(256), 0, stream, p);
  hipLaunchKernelGGL(k4_cost, dim3(1024), dim3(256), 0, stream, p);

  const double EMIN = 0.05*0.05, S2 = 0.8*0.8;
  float epsv[40]; int ne = 0;
  { double e = 16.0; while(e > EMIN){ epsv[ne++] = (float)e; e *= S2; } epsv[ne++] = (float)EMIN; }

  for(int it=0; it<ne; ++it)
    hipLaunchKernelGGL(k_iter, dim3(NBLK), dim3(256), 0, stream, p, epsv[it], it&1);

  hipLaunchKernelGGL(k_final, dim3(NBLK), dim3(256), 0, stream, p, (float)EMIN, ne&1);
  hipLaunchKernelGGL(k_out,   dim3(1),    dim3(256), 0, stream, p);
}

// Round 11
// 248.539 us; speedup vs baseline: 11.5054x; 1.1060x over previous
//
#include <hip/hip_runtime.h>

#define NN 2048
#define MM 2048
#define KC 8
#define DD 64
#define PN (NN + 4*KC + 32)
#define PM (MM + 4*KC + 32)
#define TOTROWS (2*(NN+MM))
#define CPAD (2*NN*MM + NN*NN + MM*MM + 6*(NN+MM) + 256)
#define PADV 3.0e38f
#define LN2F    0.6931471805599453f
#define INVLN2F 1.4426950408889634f
#define NBLK (TOTROWS/8)      // 1024 blocks, 4 waves/block, 2 rows/wave

// zr layout (ints): [8..15]=cnt_x, [16..23]=cnt_y, [24..31]=fill_x, [32..39]=fill_y
struct Params {
  const float* x; const float* centers; const float* ftarg;
  const float* y; const int* predy;
  float* out;
  int* zr;
  int* pred_x;
  int* cntx; int* cnty; int* off_x; int* off_y; int* pox; int* poy;
  int* bxy; int* byx; int* bxx; int* byy;    // per-cluster segment bases in Call
  int* tpre;                                 // 33-entry tile prefix table
  float* la; float* lb; int* valid; float* acc;
  float* part;                               // NBLK per-block partials (no atomics)
  float* Xp; float* Yp; float* xn; float* yn;
  float* Fab; float* Faa; float* Gab; float* Gbb;   // ping-pong 2*PN / 2*PM
  int4* meta;   // per-row {coff, hoff, rs, bitcast(hb2)}
  float* fin;   // per-row final scale (0 if invalid)
  int* dsti;    // per-row destination index in padded potential array
  float* Call;
};

__device__ __forceinline__ float wredmax(float v){
  #pragma unroll
  for(int m=32;m>=1;m>>=1) v = fmaxf(v, __shfl_xor(v,m,64));
  return v;
}
__device__ __forceinline__ float wredsum(float v){
  #pragma unroll
  for(int m=32;m>=1;m>>=1) v += __shfl_xor(v,m,64);
  return v;
}

// ---------------- k_pred: zero potentials + kmeans predict + LDS-hist counts ----------------
// G12: per-block LDS histogram -> ONE global atomic per (block,cluster). Avoids
// 4096 device-scope adds onto 2 hot lines (measured ~20ns each serialized, r7).
__global__ void __launch_bounds__(256) k_pred(Params p){
  __shared__ int hx[KC], hy[KC];
  const int tid = threadIdx.x;
  const int gtid = blockIdx.x*blockDim.x + tid;
  const int nth  = gridDim.x*blockDim.x;

  if(tid<KC){ hx[tid]=0; hy[tid]=0; }
  __syncthreads();

  for(int i=gtid;i<2*PN;i+=nth){ p.Fab[i]=0.f; p.Faa[i]=0.f; }
  for(int j=gtid;j<2*PM;j+=nth){ p.Gab[j]=0.f; p.Gbb[j]=0.f; }

  for(int i=gtid;i<NN;i+=nth){
    const float4* xi = (const float4*)(p.x + i*DD);
    float best = 3.4e38f; int bk = 0;
    for(int k=0;k<KC;k++){
      const float4* ck = (const float4*)(p.centers + k*DD);
      float s = 0.f;
      #pragma unroll
      for(int q=0;q<DD/4;q++){ float4 a=xi[q], b=ck[q];
        float dx=a.x-b.x, dy=a.y-b.y, dz=a.z-b.z, dw=a.w-b.w;
        s += dx*dx+dy*dy+dz*dz+dw*dw; }
      if(s < best){ best = s; bk = k; }
    }
    p.pred_x[i] = bk;
    atomicAdd(&hx[bk], 1);
  }
  for(int j=gtid;j<MM;j+=nth) atomicAdd(&hy[p.predy[j]], 1);
  __syncthreads();
  if(tid<KC   && hx[tid])    atomicAdd(&p.zr[8+tid], hx[tid]);
  if(tid>=KC && tid<2*KC && hy[tid-KC]) atomicAdd(&p.zr[16+tid-KC], hy[tid-KC]);
}

// ---------------- k_pack: redundant serial phase + block-reserved pack + row meta ----------------
__global__ void __launch_bounds__(256) k_pack(Params p){
  __shared__ int scx[KC], scy[KC];
  __shared__ int sox[KC+1], soy[KC+1], spx[KC], spy[KC];
  __shared__ int sbxy[KC], sbyx[KC], sbxx[KC], sbyy[KC], sval[KC];
  __shared__ float sla[KC], slb[KC];
  __shared__ int hbx[KC], hby[KC], basex[KC], basey[KC], curx[KC], cury[KC];
  const int tid = threadIdx.x;
  const int gtid = blockIdx.x*blockDim.x + tid;
  const int nth  = gridDim.x*blockDim.x;

  if(tid==0){
    int ox=0, oy=0, px=0, py=0; float lf=0.f;
    for(int k=0;k<KC;k++){
      int nk=p.zr[8+k], mk=p.zr[16+k];
      scx[k]=nk; scy[k]=mk;
      sox[k]=ox; soy[k]=oy; spx[k]=px; spy[k]=py;
      ox+=nk; oy+=mk; px=(px+nk+3)&~3; py=(py+mk+3)&~3;
      sla[k] = -logf(fmaxf((float)nk,1.f));
      slb[k] = -logf(fmaxf((float)mk,1.f));
      sval[k] = (nk>0 && mk>0)?1:0;
      float df = (float)nk/(float)NN - p.ftarg[k];
      lf += df*df;
    }
    sox[KC]=ox; soy[KC]=oy;
    int run=0;
    for(int k=0;k<KC;k++){ int nk=scx[k], mk=scy[k]; sbxy[k]=run; run+=nk*((mk+3)&~3); }
    for(int k=0;k<KC;k++){ int nk=scx[k], mk=scy[k]; sbyx[k]=run; run+=mk*((nk+3)&~3); }
    for(int k=0;k<KC;k++){ int nk=scx[k];            sbxx[k]=run; run+=nk*((nk+3)&~3); }
    for(int k=0;k<KC;k++){ int mk=scy[k];            sbyy[k]=run; run+=mk*((mk+3)&~3); }
    if(blockIdx.x==0){
      for(int k=0;k<KC;k++){
        p.cntx[k]=scx[k]; p.cnty[k]=scy[k];
        p.off_x[k]=sox[k]; p.off_y[k]=soy[k];
        p.pox[k]=spx[k]; p.poy[k]=spy[k];
        p.bxy[k]=sbxy[k]; p.byx[k]=sbyx[k]; p.bxx[k]=sbxx[k]; p.byy[k]=sbyy[k];
        p.la[k]=sla[k]; p.lb[k]=slb[k]; p.valid[k]=sval[k];
      }
      int trun=0;
      for(int e=0;e<32;e++){
        int seg=e>>3, k=e&7;
        int nk=scx[k], mk=scy[k];
        int nrows = (seg==0)?nk:(seg==1)?mk:(seg==2)?nk:mk;
        int rs    = (seg==0)?((mk+3)&~3):(seg==1)?((nk+3)&~3):(seg==2)?((nk+3)&~3):((mk+3)&~3);
        p.tpre[e]=trun;
        trun += ((nrows+63)>>6) * ((rs+63)>>6);
      }
      p.tpre[32]=trun;
      *p.acc = lf/(float)KC;
    }
  }
  if(tid<KC){ hbx[tid]=0; hby[tid]=0; curx[tid]=0; cury[tid]=0; }
  __syncthreads();

  // pass 1: this block's per-cluster counts (LDS atomics only)
  for(int i=gtid;i<NN;i+=nth) atomicAdd(&hbx[p.pred_x[i]],1);
  for(int j=gtid;j<MM;j+=nth) atomicAdd(&hby[p.predy[j]],1);
  __syncthreads();
  // reserve global ranges: ONE device atomic per (block,cluster)
  if(tid<KC){
    basex[tid] = sox[tid] + (hbx[tid] ? atomicAdd(&p.zr[24+tid], hbx[tid]) : 0);
    basey[tid] = soy[tid] + (hby[tid] ? atomicAdd(&p.zr[32+tid], hby[tid]) : 0);
  }
  __syncthreads();

  // pass 2: place points (LDS cursors; pack order within cluster is irrelevant —
  // softmin rows are permutation-invariant and meta/potentials index the packed order)
  for(int i=gtid;i<NN;i+=nth){
    int k=p.pred_x[i];
    int pos = basex[k] + atomicAdd(&curx[k],1);
    const float4* xi=(const float4*)(p.x+i*DD);
    float4* dst=(float4*)(p.Xp+(size_t)pos*DD);
    float s=0.f;
    #pragma unroll
    for(int q=0;q<DD/4;q++){ float4 v=xi[q]; dst[q]=v;
      s += v.x*v.x+v.y*v.y+v.z*v.z+v.w*v.w; }
    p.xn[pos]=s;
  }
  for(int j=gtid;j<MM;j+=nth){
    int k=p.predy[j];
    int pos = basey[k] + atomicAdd(&cury[k],1);
    const float4* yj=(const float4*)(p.y+j*DD);
    float4* dst=(float4*)(p.Yp+(size_t)pos*DD);
    float s=0.f;
    #pragma unroll
    for(int q=0;q<DD/4;q++){ float4 v=yj[q]; dst[q]=v;
      s += v.x*v.x+v.y*v.y+v.z*v.z+v.w*v.w; }
    p.yn[pos]=s;
  }

  // per-row metadata
  for(int row=gtid; row<TOTROWS; row+=nth){
    int grp = (row>=NN) + (row>=NN+MM) + (row>=2*NN+MM);
    int pidx = row - ((grp==0)?0:(grp==1)?NN:(grp==2)?(NN+MM):(2*NN+MM));
    const int* offs = (grp==0||grp==2)? sox : soy;
    int k=0;
    #pragma unroll
    for(int q=1;q<KC;q++) if(pidx>=offs[q]) k=q;
    int r = pidx - offs[k];
    int nk=scx[k], mk=scy[k];
    int rsx=(nk+3)&~3, rsy=(mk+3)&~3;
    int coff, rs, di; float hc, fv; int hoff;
    if(grp==0){ rs=rsy; coff=sbxy[k]+r*rs; hoff=spy[k]; hc=slb[k]; di=spx[k]+r;
      fv = sval[k] ?  1.f/(float)nk : 0.f; }
    else if(grp==1){ rs=rsx; coff=sbyx[k]+r*rs; hoff=spx[k]; hc=sla[k]; di=spy[k]+r;
      fv = sval[k] ?  1.f/(float)mk : 0.f; }
    else if(grp==2){ rs=rsx; coff=sbxx[k]+r*rs; hoff=spx[k]; hc=sla[k]; di=spx[k]+r;
      fv = sval[k] ? -1.f/(float)nk : 0.f; }
    else { rs=rsy; coff=sbyy[k]+r*rs; hoff=spy[k]; hc=slb[k]; di=spy[k]+r;
      fv = sval[k] ? -1.f/(float)mk : 0.f; }
    p.meta[row] = make_int4(coff, hoff, rs, __float_as_int(hc*INVLN2F));
    p.fin[row]  = fv;
    p.dsti[row] = di;
  }
}

// ---------------- k4: LDS-tiled cost build (64x64 tiles, B transposed) ----------------
__global__ void __launch_bounds__(256) k4_cost(Params p){
  __shared__ float As[64*68];
  __shared__ float Bt[64*68];
  const int tid = threadIdx.x;
  const int T = p.tpre[32];

  for(int tile=blockIdx.x; tile<T; tile+=gridDim.x){
    int e=0;
    for(int q=1;q<32;q++) if(tile>=p.tpre[q]) e=q;
    int seg=e>>3, k=e&7;
    int nk=p.cntx[k], mk=p.cnty[k];
    int rsx=(nk+3)&~3, rsy=(mk+3)&~3;
    const float *Apts, *Bpts, *nA, *nB; int nrows, ncol, rs, base;
    if(seg==0){ Apts=p.Xp+(size_t)p.off_x[k]*DD; Bpts=p.Yp+(size_t)p.off_y[k]*DD;
      nA=p.xn+p.off_x[k]; nB=p.yn+p.off_y[k]; nrows=nk; ncol=mk; rs=rsy; base=p.bxy[k]; }
    else if(seg==1){ Apts=p.Yp+(size_t)p.off_y[k]*DD; Bpts=p.Xp+(size_t)p.off_x[k]*DD;
      nA=p.yn+p.off_y[k]; nB=p.xn+p.off_x[k]; nrows=mk; ncol=nk; rs=rsx; base=p.byx[k]; }
    else if(seg==2){ Apts=p.Xp+(size_t)p.off_x[k]*DD; Bpts=Apts;
      nA=p.xn+p.off_x[k]; nB=nA; nrows=nk; ncol=nk; rs=rsx; base=p.bxx[k]; }
    else { Apts=p.Yp+(size_t)p.off_y[k]*DD; Bpts=Apts;
      nA=p.yn+p.off_y[k]; nB=nA; nrows=mk; ncol=mk; rs=rsy; base=p.byy[k]; }
    int ntc=(rs+63)>>6;
    int lt = tile - p.tpre[e];
    int tr = lt/ntc, tc = lt - tr*ntc;

    __syncthreads();
    for(int l=tid;l<1024;l+=256){
      int row=l>>4, c4=l&15;
      int gA=tr*64+row;
      float4 va = (gA<nrows)? ((const float4*)Apts)[gA*16+c4] : make_float4(0.f,0.f,0.f,0.f);
      *(float4*)&As[row*68 + c4*4] = va;
      int gB=tc*64+row;
      float4 vb = (gB<ncol)? ((const float4*)Bpts)[gB*16+c4] : make_float4(0.f,0.f,0.f,0.f);
      Bt[(c4*4+0)*68+row]=vb.x; Bt[(c4*4+1)*68+row]=vb.y;
      Bt[(c4*4+2)*68+row]=vb.z; Bt[(c4*4+3)*68+row]=vb.w;
    }
    __syncthreads();

    int tx=tid&15, ty=tid>>4;
    float4 acc[4] = {make_float4(0,0,0,0),make_float4(0,0,0,0),
                     make_float4(0,0,0,0),make_float4(0,0,0,0)};
    for(int kk=0;kk<64;kk+=4){
      float4 a0=*(float4*)&As[(ty*4+0)*68+kk];
      float4 a1=*(float4*)&As[(ty*4+1)*68+kk];
      float4 a2=*(float4*)&As[(ty*4+2)*68+kk];
      float4 a3=*(float4*)&As[(ty*4+3)*68+kk];
      float4 b0=*(float4*)&Bt[(kk+0)*68+tx*4];
      float4 b1=*(float4*)&Bt[(kk+1)*68+tx*4];
      float4 b2=*(float4*)&Bt[(kk+2)*68+tx*4];
      float4 b3=*(float4*)&Bt[(kk+3)*68+tx*4];
      #define ACCROW(i,AI) \
        acc[i].x = fmaf(AI.x,b0.x, fmaf(AI.y,b1.x, fmaf(AI.z,b2.x, fmaf(AI.w,b3.x, acc[i].x)))); \
        acc[i].y = fmaf(AI.x,b0.y, fmaf(AI.y,b1.y, fmaf(AI.z,b2.y, fmaf(AI.w,b3.y, acc[i].y)))); \
        acc[i].z = fmaf(AI.x,b0.z, fmaf(AI.y,b1.z, fmaf(AI.z,b2.z, fmaf(AI.w,b3.z, acc[i].z)))); \
        acc[i].w = fmaf(AI.x,b0.w, fmaf(AI.y,b1.w, fmaf(AI.z,b2.w, fmaf(AI.w,b3.w, acc[i].w))));
      ACCROW(0,a0) ACCROW(1,a1) ACCROW(2,a2) ACCROW(3,a3)
      #undef ACCROW
    }

    int gc0 = tc*64 + tx*4;
    #pragma unroll
    for(int i=0;i<4;i++){
      int gr = tr*64 + ty*4 + i;
      if(gr >= nrows) continue;
      float xr = nA[gr];
      float v[4]; float d[4]={acc[i].x,acc[i].y,acc[i].z,acc[i].w};
      #pragma unroll
      for(int j=0;j<4;j++){
        int gc = gc0+j;
        v[j] = PADV;
        if(gc < ncol) v[j] = 0.5f*fmaxf(xr + nB[gc] - 2.f*d[j], 0.f);
      }
      if(gc0+3 < rs){
        *(float4*)&p.Call[(size_t)base + (size_t)gr*rs + gc0] = make_float4(v[0],v[1],v[2],v[3]);
      } else {
        for(int j=0;j<4;j++) if(gc0+j < rs) p.Call[(size_t)base + (size_t)gr*rs + gc0+j] = v[j];
      }
    }
  }
}

// online-LSE stream step: one 128B chunk of one row
#define LSE_STEP(Ci,Pi,hi,mi,si) { \
  float4 cv=*(const float4*)(Ci+c0), pv=*(const float4*)(Pi+c0); \
  float w0=fmaf(pv.x-cv.x,s1,hi), w1=fmaf(pv.y-cv.y,s1,hi); \
  float w2=fmaf(pv.z-cv.z,s1,hi), w3=fmaf(pv.w-cv.w,s1,hi); \
  float lm=fmaxf(fmaxf(w0,w1),fmaxf(w2,w3)); \
  float mn=fmaxf(mi,lm); \
  si = si*exp2f(mi-mn) + (exp2f(w0-mn)+exp2f(w1-mn)) + (exp2f(w2-mn)+exp2f(w3-mn)); \
  mi = mn; }

// ---------------- k_iter: one Jacobi eps-step, 2 rows per wave (proven shape) ----------------
__global__ void __launch_bounds__(256) k_iter(Params p, float eps, int cur){
  const int w = blockIdx.x*4 + (threadIdx.x>>6);
  const int lane = threadIdx.x & 63;
  const int r0 = w*2, r1 = r0+1;
  const int grp = (r0>=NN) + (r0>=NN+MM) + (r0>=2*NN+MM);   // pairs never straddle
  const float* po; float* fam; int famN;
  if(grp==0){ po=p.Gab+cur*PM; fam=p.Fab; famN=PN; }
  else if(grp==1){ po=p.Fab+cur*PN; fam=p.Gab; famN=PM; }
  else if(grp==2){ po=p.Faa+cur*PN; fam=p.Faa; famN=PN; }
  else { po=p.Gbb+cur*PM; fam=p.Gbb; famN=PM; }

  int4 m0 = p.meta[r0], m1 = p.meta[r1];
  const float* C0=p.Call+m0.x; const float* P0=po+m0.y; float h0=__int_as_float(m0.w);
  const float* C1=p.Call+m1.x; const float* P1=po+m1.y; float h1=__int_as_float(m1.w);
  const int rs0=m0.z, rs1=m1.z, rsm = rs0>rs1?rs0:rs1;
  const float s1 = (1.0f/eps)*INVLN2F;

  float mA=-3.4e38f,sA=0.f,mB=-3.4e38f,sB=0.f;
  for(int c0=lane*4; c0<rsm; c0+=256){
    if(c0<rs0) LSE_STEP(C0,P0,h0,mA,sA)
    if(c0<rs1) LSE_STEP(C1,P1,h1,mB,sB)
  }
  float MA=wredmax(mA); float SA=wredsum(sA*exp2f(mA-MA));
  float MB=wredmax(mB); float SB=wredsum(sB*exp2f(mB-MB));
  float LA = -eps*LN2F*(MA + log2f(SA));
  float LB = -eps*LN2F*(MB + log2f(SB));

  if(lane==0){
    int d0=p.dsti[r0], d1=p.dsti[r1];
    float* fn = fam + (1-cur)*famN;
    const float* fo = fam + cur*famN;
    fn[d0] = 0.5f*(fo[d0]+LA);
    fn[d1] = 0.5f*(fo[d1]+LB);
  }
}

// ---------------- k_final: extrapolation at eps_min, per-block partial (NO atomics) ----------------
__global__ void __launch_bounds__(256) k_final(Params p, float eps, int cur){
  __shared__ float sp[4];
  const int w = blockIdx.x*4 + (threadIdx.x>>6);
  const int lane = threadIdx.x & 63;
  const int wv = threadIdx.x>>6;
  const int r0 = w*2, r1 = r0+1;
  const int grp = (r0>=NN) + (r0>=NN+MM) + (r0>=2*NN+MM);
  const float* po = (grp==0)?(p.Gab+cur*PM):(grp==1)?(p.Fab+cur*PN)
                   :(grp==2)?(p.Faa+cur*PN):(p.Gbb+cur*PM);

  int4 m0 = p.meta[r0], m1 = p.meta[r1];
  float fv0=p.fin[r0], fv1=p.fin[r1];
  const float* C0=p.Call+m0.x; const float* P0=po+m0.y; float h0=__int_as_float(m0.w);
  const float* C1=p.Call+m1.x; const float* P1=po+m1.y; float h1=__int_as_float(m1.w);
  const int rs0=m0.z, rs1=m1.z, rsm = rs0>rs1?rs0:rs1;
  const float s1 = (1.0f/eps)*INVLN2F;

  float mA=-3.4e38f,sA=0.f,mB=-3.4e38f,sB=0.f;
  for(int c0=lane*4; c0<rsm; c0+=256){
    if(c0<rs0) LSE_STEP(C0,P0,h0,mA,sA)
    if(c0<rs1) LSE_STEP(C1,P1,h1,mB,sB)
  }
  float MA=wredmax(mA); float SA=wredsum(sA*exp2f(mA-MA));
  float MB=wredmax(mB); float SB=wredsum(sB*exp2f(mB-MB));

  if(lane==0){
    float part = 0.f;
    if(fv0!=0.f) part += fv0 * (-eps*LN2F*(MA + log2f(SA)));
    if(fv1!=0.f) part += fv1 * (-eps*LN2F*(MB + log2f(SB)));
    sp[wv] = part;
  }
  __syncthreads();
  if(threadIdx.x==0)
    p.part[blockIdx.x] = sp[0]+sp[1]+sp[2]+sp[3];
}

// ---------------- k_out: sum partials + filling loss, write scalar ----------------
__global__ void __launch_bounds__(256) k_out(Params p){
  __shared__ float red[4];
  float s=0.f;
  for(int i=threadIdx.x;i<NBLK;i+=256) s += p.part[i];
  s = wredsum(s);
  if((threadIdx.x&63)==0) red[threadIdx.x>>6]=s;
  __syncthreads();
  if(threadIdx.x==0)
    p.out[0] = red[0]+red[1]+red[2]+red[3] + *p.acc;
}

extern "C" void kernel_launch(void* const* d_in, const int* in_sizes, int n_in,
                              void* d_out, int out_size, void* d_ws, size_t ws_size,
                              hipStream_t stream)
{
  Params p;
  p.x       = (const float*)d_in[0];
  p.centers = (const float*)d_in[1];
  p.ftarg   = (const float*)d_in[2];
  p.y       = (const float*)d_in[3];
  p.predy   = (const int*)d_in[4];
  p.out     = (float*)d_out;

  char* w = (char*)d_ws; size_t o = 0;
  auto A = [&](size_t bytes)->char*{ char* r = w + o; o = (o + bytes + 255) & ~(size_t)255; return r; };
  p.zr   =(int*)A(64*4);
  p.pred_x=(int*)A(NN*4);
  p.cntx =(int*)A(KC*4); p.cnty=(int*)A(KC*4);
  p.off_x=(int*)A(KC*4); p.off_y=(int*)A(KC*4);
  p.pox  =(int*)A(KC*4); p.poy =(int*)A(KC*4);
  p.bxy  =(int*)A(KC*4); p.byx =(int*)A(KC*4);
  p.bxx  =(int*)A(KC*4); p.byy =(int*)A(KC*4);
  p.tpre =(int*)A(33*4);
  p.la=(float*)A(KC*4); p.lb=(float*)A(KC*4); p.valid=(int*)A(KC*4);
  p.acc=(float*)A(4);
  p.part=(float*)A(NBLK*4);
  p.Xp=(float*)A((size_t)NN*DD*4); p.Yp=(float*)A((size_t)MM*DD*4);
  p.xn=(float*)A(NN*4); p.yn=(float*)A(MM*4);
  p.Fab=(float*)A((size_t)2*PN*4); p.Faa=(float*)A((size_t)2*PN*4);
  p.Gab=(float*)A((size_t)2*PM*4); p.Gbb=(float*)A((size_t)2*PM*4);
  p.meta=(int4*)A((size_t)TOTROWS*16);
  p.fin =(float*)A((size_t)TOTROWS*4);
  p.dsti=(int*)A((size_t)TOTROWS*4);
  p.Call=(float*)A((size_t)CPAD*4);

  hipMemsetAsync(p.zr, 0, 64*4, stream);
  hipLaunchKernelGGL(k_pred,  dim3(16),  dim3(256), 0, stream, p);
  hipLaunchKernelGGL(k_pack,  dim3(32),  dim3(256), 0, stream, p);
  hipLaunchKernelGGL(k4_cost, dim3(512), dim3(256), 0, stream, p);

  const double EMIN = 0.05*0.05, S2 = 0.8*0.8;
  float epsv[40]; int ne = 0;
  { double e = 16.0; while(e > EMIN){ epsv[ne++] = (float)e; e *= S2; } epsv[ne++] = (float)EMIN; }

  for(int it=0; it<ne; ++it)
    hipLaunchKernelGGL(k_iter, dim3(NBLK), dim3(256), 0, stream, p, epsv[it], it&1);

  hipLaunchKernelGGL(k_final, dim3(NBLK), dim3(256), 0, stream, p, (float)EMIN, ne&1);
  hipLaunchKernelGGL(k_out,   dim3(1),    dim3(256), 0, stream, p);
}